// Round 29
// baseline (63.975 us; speedup 1.0000x reference)
//
#include <hip/hip_runtime.h>

// Exponential smoothing: s[-1]=v0; s[j] = w*s[j-1] + (1-w)*x[j]; out[j]=s[j]
// w = sigmoid(smoothing_weight[h]).
// FINAL (round-28): measured best — 61.6 us. Single-pass chained scan with
// compressed publish path; values read ONCE, out written ONCE.
//   - 1024-thread blocks, 8 groups x 128 float4-ch, TS=8 steps/thread
//   - grid 1024 blocks (CL=64, NC=64); walk threads fold the block agg
//     per scalar channel directly from s_A and publish IMMEDIATELY after
//     barrier 1 (no separate fold stage / s_Ab / extra barrier)
//   - hierarchical carry walk <=7 sg + <=7 chunk polls (serial
//     poll-and-fold); sg producers publish before polling sgs
//   - inter-block comm: relaxed agent atomics + 0xFFFFFFFF sentinel only
//     (no fences); ticket keeps dependency-order = dispatch-order
//   - fixed-order folds => bit-deterministic; NT stores for out
// Falsified levers (<2us or regression): occupancy max, spill elimination,
// LDS staging, walk shape, NT-L3 retention, zero-sync multi-kernel,
// single-generation chunk-pairing. Remaining ~28us over the 33us streaming
// bound is the carry publish->poll dependency chain (memory-latency-bound,
// insensitive to all tested source-level restructuring).

namespace {

constexpr int Bt   = 16;          // batch
constexpr int Tt   = 4096;        // time
constexpr int HD4  = 128;         // float4 channels per (b,t)
constexpr int CL   = 64;          // chunk length
constexpr int NGRP = 8;           // time-groups per chunk
constexpr int TS   = CL / NGRP;   // 8 steps per group
constexpr int NC   = Tt / CL;     // 64 chunks per batch
constexpr int NBLK = NC * Bt;     // 1024
constexpr int NTHR = NGRP * HD4;  // 1024 threads
constexpr unsigned SENT = 0xFFFFFFFFu;

typedef float fvec4 __attribute__((ext_vector_type(4)));

__device__ __forceinline__ float sigmoidf_(float x) {
    return 1.0f / (1.0f + expf(-x));
}

__device__ __forceinline__ unsigned ld_relaxed(const unsigned* p) {
    return __hip_atomic_load(p, __ATOMIC_RELAXED, __HIP_MEMORY_SCOPE_AGENT);
}

__device__ __forceinline__ float poll1(const unsigned* p) {
    unsigned u = ld_relaxed(p);
    while (u == SENT) {
        __builtin_amdgcn_s_sleep(2);
        u = ld_relaxed(p);
    }
    return __uint_as_float(u);
}

__device__ __forceinline__ void store1(float* p, float v) {
    __hip_atomic_store(p, v, __ATOMIC_RELAXED, __HIP_MEMORY_SCOPE_AGENT);
}

__global__ __launch_bounds__(NTHR, 8) void ema_onepass(
    const float4* __restrict__ values4, const float* __restrict__ sw,
    const float* __restrict__ v0f, float4* __restrict__ out4,
    float* __restrict__ aggf, float* __restrict__ sgf,
    int* __restrict__ ticket) {

    __shared__ float4 s_A[NGRP][HD4];    // 16 KiB per-group partial aggs
    __shared__ float  s_carry[512];      // 2 KiB carry (scalar channels)
    __shared__ int s_vid;

    const int tid = threadIdx.x;
    if (tid == 0) s_vid = atomicAdd(ticket, 1);
    __syncthreads();
    const int vid = s_vid;
    const int b = vid & (Bt - 1);
    const int c = vid >> 4;              // chunk; deps have lower vid
    const int ch = tid & (HD4 - 1);
    const int g  = tid >> 7;             // time-group 0..7, wave-uniform

    const float w   = sigmoidf_(sw[ch >> 4]);
    const float omw = 1.0f - w;
    float W8 = w * w;  W8 = W8 * W8;  W8 = W8 * W8;       // w^8

    // Load my 8 time-steps into registers; fold zero-seed partial aggregate.
    const size_t chunkbase = ((size_t)b * Tt + (size_t)c * CL) * HD4 + ch;
    const float4* p = values4 + chunkbase + (size_t)g * TS * HD4;
    float4 x[TS];
    float4 A = make_float4(0.f, 0.f, 0.f, 0.f);
    #pragma unroll
    for (int u = 0; u < TS; ++u) {
        x[u] = p[(size_t)u * HD4];
        A.x = fmaf(w, A.x, omw * x[u].x);
        A.y = fmaf(w, A.y, omw * x[u].y);
        A.z = fmaf(w, A.z, omw * x[u].z);
        A.w = fmaf(w, A.w, omw * x[u].w);
    }
    // Pin the chunk (anti-rematerialization, rounds 5/6 lesson).
    #pragma unroll
    for (int u = 0; u < TS; ++u)
        asm volatile("" : "+v"(x[u].x), "+v"(x[u].y), "+v"(x[u].z), "+v"(x[u].w));

    s_A[g][ch] = A;
    __syncthreads();   // barrier 1 (s_A ready)

    // ---- Walk threads: fold block agg per scalar channel, publish NOW,
    //      then carry walk. Scalar channel f = tid; s_A viewed as [8][512]
    //      floats is contiguous in tid -> conflict-free LDS reads.
    if (tid < 512) {
        const float ws  = sigmoidf_(sw[tid >> 6]);
        float W8s = ws * ws;  W8s = W8s * W8s;  W8s = W8s * W8s;   // w^8
        float Wcs = W8s * W8s;  Wcs = Wcs * Wcs;  Wcs = Wcs * Wcs; // w^64
        float WSGs = Wcs;
        #pragma unroll
        for (int i = 0; i < 3; ++i) WSGs = WSGs * WSGs;            // w^512

        // Block aggregate: same fold order as r14's g==7 path => bit-equal.
        const float* sa = (const float*)s_A;   // [8][512] floats
        float ab = sa[tid];
        #pragma unroll
        for (int j = 1; j < NGRP; ++j) ab = fmaf(W8s, ab, sa[j * 512 + tid]);

        // Publish immediately (earliest possible point after barrier 1).
        store1(aggf + ((size_t)c * Bt + b) * 512 + tid, ab);

        const unsigned* au = (const unsigned*)aggf;
        const unsigned* su = (const unsigned*)sgf;
        const int mf  = c >> 3;          // complete supergroups (SG=8)
        const int k0  = mf << 3;
        const int rem = c - k0;          // 0..7

        // Phase 1: remainder scan R (seed 0), serial poll-and-fold.
        float R = 0.0f;
        #pragma unroll
        for (int j = 0; j < 7; ++j) {
            if (k0 + j < c) {
                float av = poll1(au + ((size_t)(k0 + j) * Bt + b) * 512 + tid);
                R = fmaf(Wcs, R, av);
            }
        }

        // Phase 2: supergroup producer publishes immediately (local deps).
        if ((c & 7) == 7) {
            store1(sgf + ((size_t)mf * Bt + b) * 512 + tid,
                   fmaf(Wcs, R, ab));
            asm volatile("" ::: "memory");
        }

        // Phase 3: supergroup prefix P (seed v0), serial poll-and-fold.
        float P = v0f[tid];
        #pragma unroll
        for (int j = 0; j < 7; ++j) {
            if (j < mf) {
                float svv = poll1(su + ((size_t)j * Bt + b) * 512 + tid);
                P = fmaf(WSGs, P, svv);
            }
        }

        // carry = Wc^rem * P + R   (rem in 0..7)
        float Wr = 1.0f, pw = Wcs;
        if (rem & 1) Wr *= pw;  pw *= pw;
        if (rem & 2) Wr *= pw;  pw *= pw;
        if (rem & 4) Wr *= pw;
        s_carry[tid] = fmaf(Wr, P, R);
    }
    __syncthreads();   // barrier 2 (carry ready)

    // Group seed: fold partial aggs of groups < g onto the carry.
    float4 s;
    s.x = s_carry[4 * ch + 0];
    s.y = s_carry[4 * ch + 1];
    s.z = s_carry[4 * ch + 2];
    s.w = s_carry[4 * ch + 3];
    #pragma unroll
    for (int j = 0; j < NGRP - 1; ++j) {
        if (j < g) {
            float4 Aj = s_A[j][ch];
            s.x = fmaf(W8, s.x, Aj.x);
            s.y = fmaf(W8, s.y, Aj.y);
            s.z = fmaf(W8, s.z, Aj.z);
            s.w = fmaf(W8, s.w, Aj.w);
        }
    }

    // Final scan from registers; nontemporal stream out.
    fvec4* q = (fvec4*)(out4 + chunkbase + (size_t)g * TS * HD4);
    #pragma unroll
    for (int u = 0; u < TS; ++u) {
        s.x = fmaf(w, s.x, omw * x[u].x);
        s.y = fmaf(w, s.y, omw * x[u].y);
        s.z = fmaf(w, s.z, omw * x[u].z);
        s.w = fmaf(w, s.w, omw * x[u].w);
        fvec4 sn = {s.x, s.y, s.z, s.w};
        __builtin_nontemporal_store(sn, q + (size_t)u * HD4);
    }
}

}  // namespace

extern "C" void kernel_launch(void* const* d_in, const int* in_sizes, int n_in,
                              void* d_out, int out_size, void* d_ws, size_t ws_size,
                              hipStream_t stream) {
    const float4* values4 = (const float4*)d_in[0];  // [16, 4096, 8, 64] f32
    const float*  sw      = (const float*)d_in[1];   // [8, 1]
    const float*  v0f     = (const float*)d_in[2];   // [1, 1, 8, 64] = 512 f32
    float4* out4 = (float4*)d_out;

    const size_t aggFloats = (size_t)NC * Bt * 512;        // 2 MiB
    const size_t sgFloats  = (size_t)(NC / 8) * Bt * 512;  // 256 KiB
    float* aggf   = (float*)d_ws;
    float* sgf    = aggf + aggFloats;
    int*   ticket = (int*)(sgf + sgFloats);

    (void)hipMemsetAsync(aggf, 0xFF, (aggFloats + sgFloats) * sizeof(float), stream);
    (void)hipMemsetAsync(ticket, 0, sizeof(int), stream);

    ema_onepass<<<dim3(NBLK), dim3(NTHR), 0, stream>>>(values4, sw, v0f, out4,
                                                       aggf, sgf, ticket);
}

// Round 30
// 61.508 us; speedup vs baseline: 1.0401x; 1.0401x over previous
//
#include <hip/hip_runtime.h>

// Exponential smoothing: s[-1]=v0; s[j] = w*s[j-1] + (1-w)*x[j]; out[j]=s[j]
// w = sigmoid(smoothing_weight[h]).
// FINAL (round-28): measured best — 61.6 us (reconfirmed 64.0). Single-pass
// chained scan with compressed publish path; values read ONCE, out written
// ONCE.
//   - 1024-thread blocks, 8 groups x 128 float4-ch, TS=8 steps/thread
//   - grid 1024 blocks (CL=64, NC=64); walk threads fold the block agg
//     per scalar channel directly from s_A and publish IMMEDIATELY after
//     barrier 1 (no separate fold stage / s_Ab / extra barrier)
//   - hierarchical carry walk <=7 sg + <=7 chunk polls (serial
//     poll-and-fold); sg producers publish before polling sgs
//   - inter-block comm: relaxed agent atomics + 0xFFFFFFFF sentinel only
//     (no fences); ticket keeps dependency-order = dispatch-order
//   - fixed-order folds => bit-deterministic; NT stores for out
// Falsified levers (<2us or regression): occupancy max, spill elimination,
// LDS staging, walk shape, NT-L3 retention, zero-sync multi-kernel,
// single-generation chunk-pairing, publish-path compression (+0.3..2us).
// Remaining ~20us over the ~41us streaming bound is the carry publish->poll
// dependency chain (memory-latency-bound, insensitive to all tested
// source-level restructuring).

namespace {

constexpr int Bt   = 16;          // batch
constexpr int Tt   = 4096;        // time
constexpr int HD4  = 128;         // float4 channels per (b,t)
constexpr int CL   = 64;          // chunk length
constexpr int NGRP = 8;           // time-groups per chunk
constexpr int TS   = CL / NGRP;   // 8 steps per group
constexpr int NC   = Tt / CL;     // 64 chunks per batch
constexpr int NBLK = NC * Bt;     // 1024
constexpr int NTHR = NGRP * HD4;  // 1024 threads
constexpr unsigned SENT = 0xFFFFFFFFu;

typedef float fvec4 __attribute__((ext_vector_type(4)));

__device__ __forceinline__ float sigmoidf_(float x) {
    return 1.0f / (1.0f + expf(-x));
}

__device__ __forceinline__ unsigned ld_relaxed(const unsigned* p) {
    return __hip_atomic_load(p, __ATOMIC_RELAXED, __HIP_MEMORY_SCOPE_AGENT);
}

__device__ __forceinline__ float poll1(const unsigned* p) {
    unsigned u = ld_relaxed(p);
    while (u == SENT) {
        __builtin_amdgcn_s_sleep(2);
        u = ld_relaxed(p);
    }
    return __uint_as_float(u);
}

__device__ __forceinline__ void store1(float* p, float v) {
    __hip_atomic_store(p, v, __ATOMIC_RELAXED, __HIP_MEMORY_SCOPE_AGENT);
}

__global__ __launch_bounds__(NTHR, 8) void ema_onepass(
    const float4* __restrict__ values4, const float* __restrict__ sw,
    const float* __restrict__ v0f, float4* __restrict__ out4,
    float* __restrict__ aggf, float* __restrict__ sgf,
    int* __restrict__ ticket) {

    __shared__ float4 s_A[NGRP][HD4];    // 16 KiB per-group partial aggs
    __shared__ float  s_carry[512];      // 2 KiB carry (scalar channels)
    __shared__ int s_vid;

    const int tid = threadIdx.x;
    if (tid == 0) s_vid = atomicAdd(ticket, 1);
    __syncthreads();
    const int vid = s_vid;
    const int b = vid & (Bt - 1);
    const int c = vid >> 4;              // chunk; deps have lower vid
    const int ch = tid & (HD4 - 1);
    const int g  = tid >> 7;             // time-group 0..7, wave-uniform

    const float w   = sigmoidf_(sw[ch >> 4]);
    const float omw = 1.0f - w;
    float W8 = w * w;  W8 = W8 * W8;  W8 = W8 * W8;       // w^8

    // Load my 8 time-steps into registers; fold zero-seed partial aggregate.
    const size_t chunkbase = ((size_t)b * Tt + (size_t)c * CL) * HD4 + ch;
    const float4* p = values4 + chunkbase + (size_t)g * TS * HD4;
    float4 x[TS];
    float4 A = make_float4(0.f, 0.f, 0.f, 0.f);
    #pragma unroll
    for (int u = 0; u < TS; ++u) {
        x[u] = p[(size_t)u * HD4];
        A.x = fmaf(w, A.x, omw * x[u].x);
        A.y = fmaf(w, A.y, omw * x[u].y);
        A.z = fmaf(w, A.z, omw * x[u].z);
        A.w = fmaf(w, A.w, omw * x[u].w);
    }
    // Pin the chunk (anti-rematerialization, rounds 5/6 lesson).
    #pragma unroll
    for (int u = 0; u < TS; ++u)
        asm volatile("" : "+v"(x[u].x), "+v"(x[u].y), "+v"(x[u].z), "+v"(x[u].w));

    s_A[g][ch] = A;
    __syncthreads();   // barrier 1 (s_A ready)

    // ---- Walk threads: fold block agg per scalar channel, publish NOW,
    //      then carry walk. Scalar channel f = tid; s_A viewed as [8][512]
    //      floats is contiguous in tid -> conflict-free LDS reads.
    if (tid < 512) {
        const float ws  = sigmoidf_(sw[tid >> 6]);
        float W8s = ws * ws;  W8s = W8s * W8s;  W8s = W8s * W8s;   // w^8
        float Wcs = W8s * W8s;  Wcs = Wcs * Wcs;  Wcs = Wcs * Wcs; // w^64
        float WSGs = Wcs;
        #pragma unroll
        for (int i = 0; i < 3; ++i) WSGs = WSGs * WSGs;            // w^512

        // Block aggregate: same fold order as r14's g==7 path => bit-equal.
        const float* sa = (const float*)s_A;   // [8][512] floats
        float ab = sa[tid];
        #pragma unroll
        for (int j = 1; j < NGRP; ++j) ab = fmaf(W8s, ab, sa[j * 512 + tid]);

        // Publish immediately (earliest possible point after barrier 1).
        store1(aggf + ((size_t)c * Bt + b) * 512 + tid, ab);

        const unsigned* au = (const unsigned*)aggf;
        const unsigned* su = (const unsigned*)sgf;
        const int mf  = c >> 3;          // complete supergroups (SG=8)
        const int k0  = mf << 3;
        const int rem = c - k0;          // 0..7

        // Phase 1: remainder scan R (seed 0), serial poll-and-fold.
        float R = 0.0f;
        #pragma unroll
        for (int j = 0; j < 7; ++j) {
            if (k0 + j < c) {
                float av = poll1(au + ((size_t)(k0 + j) * Bt + b) * 512 + tid);
                R = fmaf(Wcs, R, av);
            }
        }

        // Phase 2: supergroup producer publishes immediately (local deps).
        if ((c & 7) == 7) {
            store1(sgf + ((size_t)mf * Bt + b) * 512 + tid,
                   fmaf(Wcs, R, ab));
            asm volatile("" ::: "memory");
        }

        // Phase 3: supergroup prefix P (seed v0), serial poll-and-fold.
        float P = v0f[tid];
        #pragma unroll
        for (int j = 0; j < 7; ++j) {
            if (j < mf) {
                float svv = poll1(su + ((size_t)j * Bt + b) * 512 + tid);
                P = fmaf(WSGs, P, svv);
            }
        }

        // carry = Wc^rem * P + R   (rem in 0..7)
        float Wr = 1.0f, pw = Wcs;
        if (rem & 1) Wr *= pw;  pw *= pw;
        if (rem & 2) Wr *= pw;  pw *= pw;
        if (rem & 4) Wr *= pw;
        s_carry[tid] = fmaf(Wr, P, R);
    }
    __syncthreads();   // barrier 2 (carry ready)

    // Group seed: fold partial aggs of groups < g onto the carry.
    float4 s;
    s.x = s_carry[4 * ch + 0];
    s.y = s_carry[4 * ch + 1];
    s.z = s_carry[4 * ch + 2];
    s.w = s_carry[4 * ch + 3];
    #pragma unroll
    for (int j = 0; j < NGRP - 1; ++j) {
        if (j < g) {
            float4 Aj = s_A[j][ch];
            s.x = fmaf(W8, s.x, Aj.x);
            s.y = fmaf(W8, s.y, Aj.y);
            s.z = fmaf(W8, s.z, Aj.z);
            s.w = fmaf(W8, s.w, Aj.w);
        }
    }

    // Final scan from registers; nontemporal stream out.
    fvec4* q = (fvec4*)(out4 + chunkbase + (size_t)g * TS * HD4);
    #pragma unroll
    for (int u = 0; u < TS; ++u) {
        s.x = fmaf(w, s.x, omw * x[u].x);
        s.y = fmaf(w, s.y, omw * x[u].y);
        s.z = fmaf(w, s.z, omw * x[u].z);
        s.w = fmaf(w, s.w, omw * x[u].w);
        fvec4 sn = {s.x, s.y, s.z, s.w};
        __builtin_nontemporal_store(sn, q + (size_t)u * HD4);
    }
}

}  // namespace

extern "C" void kernel_launch(void* const* d_in, const int* in_sizes, int n_in,
                              void* d_out, int out_size, void* d_ws, size_t ws_size,
                              hipStream_t stream) {
    const float4* values4 = (const float4*)d_in[0];  // [16, 4096, 8, 64] f32
    const float*  sw      = (const float*)d_in[1];   // [8, 1]
    const float*  v0f     = (const float*)d_in[2];   // [1, 1, 8, 64] = 512 f32
    float4* out4 = (float4*)d_out;

    const size_t aggFloats = (size_t)NC * Bt * 512;        // 2 MiB
    const size_t sgFloats  = (size_t)(NC / 8) * Bt * 512;  // 256 KiB
    float* aggf   = (float*)d_ws;
    float* sgf    = aggf + aggFloats;
    int*   ticket = (int*)(sgf + sgFloats);

    (void)hipMemsetAsync(aggf, 0xFF, (aggFloats + sgFloats) * sizeof(float), stream);
    (void)hipMemsetAsync(ticket, 0, sizeof(int), stream);

    ema_onepass<<<dim3(NBLK), dim3(NTHR), 0, stream>>>(values4, sw, v0f, out4,
                                                       aggf, sgf, ticket);
}